// Round 13
// baseline (9269.091 us; speedup 1.0000x reference)
//
#include <hip/hip_runtime.h>
#include <math.h>

#define NCLS 80
#define KTOP 1000
#define SCORE_T 0.05f
#define NMS_T 0.6f
#define SCALE_CLAMP 4.135166556742356f
#define IMGW 1344.0f
#define IMGH 1024.0f

// ----------------------------------------------------------------------------
// Multi-level 3x3 same-pad conv, Cin=256, dual-tower via z. 256 thr ->
// (16*CC) couts x (8x16) tile; thread: CC couts x (2x4) pos. ci-block 16
// (r13: halves barriers vs r12's 8), LDS input double-buffer (1 barrier per
// rstep, 16 rsteps). Weights via running pointers (+144/rstep) and explicit
// component fmaf chain (r10-12 proven). 1-D grid with XCD-aware decode
// (r11-proven: FETCH -48%). FMA order per output: ci asc, (dy,dx) asc,
// fmaf — bit-identical to r4..r12.
// ----------------------------------------------------------------------------
struct MCfg {
    const float* feat[5];
    long offIn[5];
    long offOutA[5];
    long offOutB[5];
    int tileBase[6];
    int tilesX[5];
    int Hs[5];
    int Ws[5];
    int nLvl;
    int useFeats;
};

template<int RELU, int CC>
__global__ __launch_bounds__(256)
void conv_g(MCfg cfg,
            const float* __restrict__ inA, const float* __restrict__ inB,
            const float* __restrict__ wA, const float* __restrict__ wB,
            const float* __restrict__ bA, const float* __restrict__ bB,
            float* __restrict__ outA, float* __restrict__ outB,
            int CoutA, int CoutB, int zA, int zOff, int nTiles, int NZ)
{
    __shared__ float sIn[2][16][10][20];
    const int tid = threadIdx.x;

    // XCD-aware block decode: tile % 8 == blockIdx.x % 8 (same-XCD grouping)
    const int bx   = blockIdx.x;
    const int xcd  = bx & 7;
    const int rest = bx >> 3;
    const int perT = 2 * NZ;
    const int tgroup = rest / perT;
    const int k      = rest - tgroup * perT;
    const int tile   = tgroup * 8 + xcd;
    if (tile >= nTiles) return;
    const int n     = k / NZ;
    const int z_eff = (k - n * NZ) + zOff;

    const bool isA = (z_eff < zA);
    const float* wt   = isA ? wA : wB;
    const float* bias = isA ? bA : bB;
    const int Cout    = isA ? CoutA : CoutB;
    const int cbase   = (isA ? z_eff : z_eff - zA) * (16 * CC);

    int tl = tile;
    int lvl = 0;
    while (lvl + 1 < cfg.nLvl && tl >= cfg.tileBase[lvl + 1]) ++lvl;
    int t = tl - cfg.tileBase[lvl];
    const int tX = cfg.tilesX[lvl];
    int ty = 0;
    while (t >= tX) { t -= tX; ++ty; }
    const int tx = t;
    const int H = cfg.Hs[lvl], W = cfg.Ws[lvl], HW = H * W;
    const float* inbase = cfg.useFeats ? cfg.feat[lvl]
                                       : ((isA ? inA : inB) + cfg.offIn[lvl]);
    const float* inN = inbase + (size_t)n * 256 * HW;

    const int h0 = ty * 8, w0 = tx * 16;
    const int cell = tid & 15, cg = tid >> 4;
    const int pr = (cell >> 2) << 1;   // 0,2,4,6
    const int pc = (cell & 3) << 2;    // 0,4,8,12
    const int q = tid & 3, pp0 = tid >> 2;

    const int cout_my = cbase + cg * CC;
    // running weight pointers, bumped +144 floats per rstep (16 ci x 9)
    const float* wptr[CC];
#pragma unroll
    for (int cc = 0; cc < CC; ++cc) {
        int gc = cout_my + cc;
        int gcw = (gc < Cout) ? gc : 0;
        wptr[cc] = wt + (size_t)gcw * 2304;
    }

    float acc[CC][8];
#pragma unroll
    for (int a = 0; a < CC; ++a)
#pragma unroll
        for (int b = 0; b < 8; ++b) acc[a][b] = 0.f;

    float rIn[15];

    auto issue = [&](int ci0) {
#pragma unroll
        for (int it = 0; it < 3; ++it) {
            int p = pp0 + it * 64;
            if (p < 160) {
                int ci = p / 10, row = p - ci * 10;
                int gh = h0 + row - 1;
                const float* src = inN + (size_t)(ci0 + ci) * HW;
#pragma unroll
                for (int j = 0; j < 5; ++j) {
                    int col = q * 5 + j, gw = w0 + col - 1;
                    float v = 0.f;
                    if (col < 18 && (unsigned)gh < (unsigned)H && (unsigned)gw < (unsigned)W)
                        v = src[(long)gh * W + gw];
                    rIn[it * 5 + j] = v;
                }
            }
        }
    };
    auto commit = [&](int buf) {
#pragma unroll
        for (int it = 0; it < 3; ++it) {
            int p = pp0 + it * 64;
            if (p < 160) {
                int ci = p / 10, row = p - ci * 10;
#pragma unroll
                for (int j = 0; j < 5; ++j)
                    sIn[buf][ci][row][q * 5 + j] = rIn[it * 5 + j];  // cols 18,19 = pad
            }
        }
    };

    issue(0);
    commit(0);
    __syncthreads();

    for (int r = 0; r < 16; ++r) {
        if (r < 15) issue((r + 1) * 16);
        const int cur = r & 1;
#pragma unroll 2
        for (int ci = 0; ci < 16; ++ci) {
            float x[4][6];
#pragma unroll
            for (int rr = 0; rr < 4; ++rr)
#pragma unroll
                for (int c = 0; c < 6; ++c) x[rr][c] = sIn[cur][ci][pr + rr][pc + c];
#pragma unroll
            for (int cc = 0; cc < CC; ++cc) {
                const float* wp = wptr[cc] + ci * 9;   // ci*9 folds to imm offset
                float4 wa = *(const float4*)(wp);
                float4 wb = *(const float4*)(wp + 4);
                float w8 = wp[8];
#pragma unroll
                for (int py = 0; py < 2; ++py)
#pragma unroll
                    for (int px = 0; px < 4; ++px) {
                        float s = acc[cc][py * 4 + px];
                        // (dy,dx) ascending — identical order to wv[dy*3+dx]
                        s = fmaf(wa.x, x[py + 0][px + 0], s);
                        s = fmaf(wa.y, x[py + 0][px + 1], s);
                        s = fmaf(wa.z, x[py + 0][px + 2], s);
                        s = fmaf(wa.w, x[py + 1][px + 0], s);
                        s = fmaf(wb.x, x[py + 1][px + 1], s);
                        s = fmaf(wb.y, x[py + 1][px + 2], s);
                        s = fmaf(wb.z, x[py + 2][px + 0], s);
                        s = fmaf(wb.w, x[py + 2][px + 1], s);
                        s = fmaf(w8,   x[py + 2][px + 2], s);
                        acc[cc][py * 4 + px] = s;
                    }
            }
        }
#pragma unroll
        for (int cc = 0; cc < CC; ++cc) wptr[cc] += 144;
        if (r < 15) commit((r + 1) & 1);
        __syncthreads();
    }

    float* outbase = isA ? (outA + cfg.offOutA[lvl]) : (outB + cfg.offOutB[lvl]);
#pragma unroll
    for (int cc = 0; cc < CC; ++cc) {
        int gc = cout_my + cc;
        if (gc >= Cout) continue;
        float b = bias[gc];
        float* outc = outbase + ((size_t)n * Cout + gc) * HW;
#pragma unroll
        for (int py = 0; py < 2; ++py) {
            int gh = h0 + pr + py;
            if (gh >= H) continue;
#pragma unroll
            for (int px = 0; px < 4; ++px) {
                int gw = w0 + pc + px;
                if (gw >= W) continue;
                float v = acc[cc][py * 4 + px] + b;
                if (RELU) v = fmaxf(v, 0.f);
                outc[(long)gh * W + gw] = v;
            }
        }
    }
}

// ----------------------------------------------------------------------------
__global__ void pack_kernel(const float* __restrict__ sw, const float* __restrict__ sb,
                            const float* __restrict__ cw, const float* __restrict__ cb,
                            float* __restrict__ pw, float* __restrict__ pb)
{
    int i = blockIdx.x * 256 + threadIdx.x;
    const int tot = 81 * 2304;
    if (i < tot) pw[i] = (i < 80 * 2304) ? sw[i] : cw[i - 80 * 2304];
    if (i < 81)  pb[i] = (i < 80) ? sb[i] : cb[i - 80];
}

// ----------------------------------------------------------------------------
// batched selection pipeline (unchanged, proven absmax 0.0)
// ----------------------------------------------------------------------------
struct LvlT {
    int HW[5]; int W[5]; float stride[5];
    long off81[5]; long offD[5];
};

__device__ inline float score_at(const float* __restrict__ L, int HW, int c, int pos)
{
    float l = L[(size_t)c * HW + pos];
    float ct = L[(size_t)80 * HW + pos];
    float sl = 1.f / (1.f + expf(-l));
    float sc = 1.f / (1.f + expf(-ct));
    return sqrtf(sl * sc);
}

__global__ __launch_bounds__(256)
void hist_b(LvlT T, const float* __restrict__ lg, unsigned* __restrict__ hist,
            const int* __restrict__ sel, int pass)
{
    __shared__ unsigned h[4096];
    int n = blockIdx.y, lvl = blockIdx.z, g = lvl * 2 + n;
    int HW = T.HW[lvl];
    int nel = HW * 80;
    const float* L = lg + T.off81[lvl] + (size_t)n * 81 * HW;
    unsigned* Hh = hist + g * 4096;
    const int* SL = sel + g * 8;
    for (int i = threadIdx.x; i < 4096; i += 256) h[i] = 0;
    __syncthreads();
    unsigned b1 = 0, b2 = 0;
    if (pass >= 1) b1 = (unsigned)SL[0];
    if (pass == 2) b2 = (unsigned)SL[2];
    int stride = gridDim.x * 256;
    for (int i = blockIdx.x * 256 + threadIdx.x; i < nel; i += stride) {
        int c = i / HW, pos = i - c * HW;
        unsigned bits = __float_as_uint(score_at(L, HW, c, pos));
        if (pass == 0) atomicAdd(&h[bits >> 24], 1u);
        else if (pass == 1) { if ((bits >> 24) == b1) atomicAdd(&h[(bits >> 12) & 0xFFFu], 1u); }
        else { if ((bits >> 12) == ((b1 << 12) | b2)) atomicAdd(&h[bits & 0xFFFu], 1u); }
    }
    __syncthreads();
    for (int i = threadIdx.x; i < 4096; i += 256)
        if (h[i]) atomicAdd(&Hh[i], h[i]);
}

__global__ __launch_bounds__(1024)
void scan_b(const unsigned* __restrict__ hist, int* __restrict__ sel, int pass)
{
    __shared__ unsigned ps[1024];
    int g = blockIdx.x;
    const unsigned* H = hist + g * 4096;
    int* SL = sel + g * 8;
    int tid = threadIdx.x;
    unsigned s = 0;
    if (pass == 0) s = (tid < 256) ? H[tid] : 0u;
    else { for (int b = 0; b < 4; ++b) s += H[tid * 4 + b]; }
    ps[tid] = s;
    __syncthreads();
    if (tid == 0) {
        unsigned base = 0;
        if (pass == 1) base = (unsigned)SL[1];
        else if (pass == 2) base = (unsigned)SL[3];
        unsigned cum = base, prev = 0;
        int fb = -1;
        for (int t = 1023; t >= 0; --t) {
            if (cum + ps[t] >= (unsigned)KTOP) {
                if (pass == 0) { fb = t; prev = cum; }
                else {
                    for (int b = t * 4 + 3; b >= t * 4; --b) {
                        unsigned c = H[b];
                        if (cum + c >= (unsigned)KTOP) { fb = b; prev = cum; break; }
                        cum += c;
                    }
                }
                break;
            }
            cum += ps[t];
        }
        if (pass == 0) { SL[0] = fb; SL[1] = (int)prev; }
        else if (pass == 1) { SL[2] = fb; SL[3] = (int)prev; }
        else {
            unsigned T = (((unsigned)SL[0]) << 24) | (((unsigned)SL[2]) << 12) | (unsigned)fb;
            SL[4] = (int)T; SL[5] = KTOP - (int)prev; SL[6] = (int)prev;
        }
    }
}

__global__ __launch_bounds__(256)
void compact_b(LvlT T, const float* __restrict__ lg, const int* __restrict__ sel,
               int* __restrict__ candIdx, float* __restrict__ candScore,
               unsigned* __restrict__ eqList, int* __restrict__ counters)
{
    int n = blockIdx.y, lvl = blockIdx.z, g = lvl * 2 + n;
    int HW = T.HW[lvl];
    int nel = HW * 80;
    const float* L = lg + T.off81[lvl] + (size_t)n * 81 * HW;
    unsigned Tt = (unsigned)sel[g * 8 + 4];
    int* cnt = counters + g * 2;
    int stride = gridDim.x * 256;
    for (int i = blockIdx.x * 256 + threadIdx.x; i < nel; i += stride) {
        int c = i / HW, pos = i - c * HW;
        float v = score_at(L, HW, c, pos);
        unsigned bits = __float_as_uint(v);
        int flat = pos * 80 + c;
        if (bits > Tt) {
            int s = atomicAdd(&cnt[0], 1);
            if (s < KTOP) {
                candIdx[n * 5000 + lvl * 1000 + s] = flat;
                candScore[n * 5000 + lvl * 1000 + s] = v;
            }
        } else if (bits == Tt) {
            int e = atomicAdd(&cnt[1], 1);
            if (e < 4096) eqList[g * 4096 + e] = (unsigned)flat;
        }
    }
}

template<typename T>
__device__ inline void bitonicSort(T* a, int N, bool desc)
{
    for (int k = 2; k <= N; k <<= 1)
        for (int j = k >> 1; j >= 1; j >>= 1) {
            for (int i = threadIdx.x; i < N; i += blockDim.x) {
                int l = i ^ j;
                if (l > i) {
                    T x = a[i], y = a[l];
                    bool up = ((i & k) == 0);
                    bool sw = desc ? (up ? (x < y) : (x > y)) : (up ? (x > y) : (x < y));
                    if (sw) { a[i] = y; a[l] = x; }
                }
            }
            __syncthreads();
        }
}

__global__ __launch_bounds__(256)
void eqfinish_b(const unsigned* __restrict__ eqList, const int* __restrict__ sel,
                const int* __restrict__ counters, int* __restrict__ candIdx,
                float* __restrict__ candScore)
{
    __shared__ unsigned L[4096];
    int g = blockIdx.x;
    int lvl = g >> 1, n = g & 1;
    int e = counters[g * 2 + 1]; if (e > 4096) e = 4096;
    int needEq = sel[g * 8 + 5];
    int base = sel[g * 8 + 6];
    unsigned T = (unsigned)sel[g * 8 + 4];
    for (int i = threadIdx.x; i < 4096; i += 256) L[i] = (i < e) ? eqList[g * 4096 + i] : 0xFFFFFFFFu;
    __syncthreads();
    bitonicSort(L, 4096, false);
    for (int t = threadIdx.x; t < needEq; t += 256) {
        int s = base + t;
        if (s < KTOP) {
            candIdx[n * 5000 + lvl * 1000 + s] = (int)L[t];
            candScore[n * 5000 + lvl * 1000 + s] = __uint_as_float(T);
        }
    }
}

__global__ __launch_bounds__(256)
void lvlsort_b(int* __restrict__ candIdx, float* __restrict__ candScore)
{
    __shared__ unsigned long long K[1024];
    int g = blockIdx.x;
    int lvl = g >> 1, n = g & 1;
    int* CI = candIdx + n * 5000 + lvl * 1000;
    float* CS = candScore + n * 5000 + lvl * 1000;
    for (int i = threadIdx.x; i < 1024; i += blockDim.x)
        K[i] = (i < KTOP)
             ? ((((unsigned long long)(unsigned)CI[i]) << 32) | __float_as_uint(CS[i]))
             : 0xFFFFFFFFFFFFFFFFULL;
    __syncthreads();
    bitonicSort(K, 1024, false);
    for (int i = threadIdx.x; i < KTOP; i += blockDim.x) {
        CI[i] = (int)(K[i] >> 32);
        CS[i] = __uint_as_float((unsigned)(K[i] & 0xFFFFFFFFu));
    }
}

__global__ __launch_bounds__(256)
void decode_b(LvlT T, const int* __restrict__ candIdx, const float* __restrict__ candScore,
              const float* __restrict__ deltas, float* __restrict__ candBox,
              float* __restrict__ candZ, int* __restrict__ candCls)
{
    int t = blockIdx.x * 256 + threadIdx.x;
    if (t >= 2 * 5000) return;
    int n = t / 5000, r = t % 5000;
    int lvl = r / 1000;
    int HW = T.HW[lvl], W = T.W[lvl];
    float stride = T.stride[lvl];
    int g = n * 5000 + r;
    int idx = candIdx[g];
    float raw = candScore[g];
    int pos = idx / NCLS, cls = idx % NCLS;
    int hh = pos / W, ww = pos % W;
    float cxa0 = ((float)ww + 0.5f) * stride;
    float cya0 = ((float)hh + 0.5f) * stride;
    float half = 2.f * stride;
    float a0 = cxa0 - half, a1 = cya0 - half, a2 = cxa0 + half, a3 = cya0 + half;
    float wa = a2 - a0, ha = a3 - a1;
    float cxa = a0 + 0.5f * wa, cya = a1 + 0.5f * ha;
    const float* D = deltas + T.offD[lvl] + (size_t)n * 4 * HW;
    float dx = D[pos], dy = D[HW + pos], dw = D[2 * HW + pos], dh = D[3 * HW + pos];
    dw = fminf(dw, SCALE_CLAMP); dh = fminf(dh, SCALE_CLAMP);
    float cx = dx * wa + cxa, cy = dy * ha + cya;
    float w2 = expf(dw) * wa, h2 = expf(dh) * ha;
    float x1 = fminf(fmaxf(cx - 0.5f * w2, 0.f), IMGW);
    float y1 = fminf(fmaxf(cy - 0.5f * h2, 0.f), IMGH);
    float x2 = fminf(fmaxf(cx + 0.5f * w2, 0.f), IMGW);
    float y2 = fminf(fmaxf(cy + 0.5f * h2, 0.f), IMGH);
    candBox[g * 4 + 0] = x1; candBox[g * 4 + 1] = y1;
    candBox[g * 4 + 2] = x2; candBox[g * 4 + 3] = y2;
    candZ[g] = (raw > SCORE_T) ? raw : 0.f;
    candCls[g] = cls;
}

__global__ __launch_bounds__(1024)
void gsort_kernel(const float* __restrict__ candZ, const float* __restrict__ candBox,
                  const int* __restrict__ candCls, float* __restrict__ sBox,
                  float* __restrict__ sScore, float* __restrict__ sCls,
                  float* __restrict__ sOffB, float* __restrict__ sArea)
{
    __shared__ unsigned long long K[8192];
    int n = blockIdx.x;
    for (int i = threadIdx.x; i < 8192; i += 1024)
        K[i] = (i < 5000)
             ? ((((unsigned long long)__float_as_uint(candZ[n * 5000 + i])) << 16)
                | (unsigned long long)(65535 - i))
             : 0ULL;
    __syncthreads();
    bitonicSort(K, 8192, true);
    for (int r = threadIdx.x; r < 5000; r += 1024) {
        unsigned long long k = K[r];
        int g = 65535 - (int)(k & 0xFFFFULL);
        float s = __uint_as_float((unsigned)((k >> 16) & 0xFFFFFFFFULL));
        int cls = candCls[n * 5000 + g];
        float b0 = candBox[(n * 5000 + g) * 4 + 0];
        float b1 = candBox[(n * 5000 + g) * 4 + 1];
        float b2 = candBox[(n * 5000 + g) * 4 + 2];
        float b3 = candBox[(n * 5000 + g) * 4 + 3];
        size_t o = (size_t)n * 5000 + r;
        sBox[o * 4 + 0] = b0; sBox[o * 4 + 1] = b1; sBox[o * 4 + 2] = b2; sBox[o * 4 + 3] = b3;
        sScore[o] = s;
        sCls[o] = (float)cls;
        float off = (float)cls * 2000.0f;
        float o0 = b0 + off, o1 = b1 + off, o2 = b2 + off, o3 = b3 + off;
        sOffB[o * 4 + 0] = o0; sOffB[o * 4 + 1] = o1; sOffB[o * 4 + 2] = o2; sOffB[o * 4 + 3] = o3;
        sArea[o] = (o2 - o0) * (o3 - o1);
    }
}

__global__ __launch_bounds__(64)
void nms_mask_kernel(const float* __restrict__ sOffB, const float* __restrict__ sArea,
                     unsigned long long* __restrict__ masks)
{
    __shared__ float jb0[64], jb1[64], jb2[64], jb3[64], ja[64];
    int jw = blockIdx.x;
    int it = blockIdx.y;
    int n  = blockIdx.z;
    int t = threadIdx.x;
    int jj = jw * 64 + t;
    const float* B = sOffB + (size_t)n * 5000 * 4;
    const float* A = sArea + (size_t)n * 5000;
    if (jj < 5000) {
        jb0[t] = B[jj * 4]; jb1[t] = B[jj * 4 + 1];
        jb2[t] = B[jj * 4 + 2]; jb3[t] = B[jj * 4 + 3];
        ja[t] = A[jj];
    } else {
        jb0[t] = -3e8f; jb1[t] = -3e8f; jb2[t] = -3e8f; jb3[t] = -3e8f; ja[t] = 0.f;
    }
    __syncthreads();
    int i = it * 64 + t;
    if (i >= 5000) return;
    float b0 = B[i * 4], b1 = B[i * 4 + 1], b2 = B[i * 4 + 2], b3 = B[i * 4 + 3];
    float ai = A[i];
    unsigned long long m = 0;
    for (int u = 0; u < 64; ++u) {
        float xx1 = fmaxf(b0, jb0[u]);
        float yy1 = fmaxf(b1, jb1[u]);
        float xx2 = fminf(b2, jb2[u]);
        float yy2 = fminf(b3, jb3[u]);
        float iw = fmaxf(xx2 - xx1, 0.f), ih = fmaxf(yy2 - yy1, 0.f);
        float inter = iw * ih;
        float iou = inter / (ai + ja[u] - inter + 1e-9f);
        if (iou > NMS_T) m |= (1ull << u);
    }
    masks[((size_t)n * 5000 + i) * 79 + jw] = m;
}

__global__ __launch_bounds__(128)
void nms_scan_kernel(const unsigned long long* __restrict__ masks,
                     const float* __restrict__ sScore, const float* __restrict__ sBox,
                     const float* __restrict__ sCls, float* __restrict__ out)
{
    __shared__ unsigned long long rem[80];
    __shared__ int alive[100], dead[100];
    __shared__ int st[3];
    int n = blockIdx.x, t = threadIdx.x;
    const float* S = sScore + (size_t)n * 5000;
    for (int i = t; i < 80; i += 128) rem[i] = 0ull;
    if (t == 0) { st[0] = 0; st[1] = 0; }
    __syncthreads();
    for (int i = 0; i < 5000; ++i) {
        if (t == 0) {
            bool sup = (rem[i >> 6] >> (i & 63)) & 1ull;
            float s = S[i];
            bool al = (!sup) && (s > 0.f);
            st[2] = al ? 1 : 0;
            if (al) { if (st[0] < 100) alive[st[0]] = i; st[0]++; }
            else    { if (st[1] < 100) dead[st[1]] = i;  st[1]++; }
        }
        __syncthreads();
        bool stop = (st[0] >= 100);
        if (st[2] && !stop) {
            const unsigned long long* row = masks + ((size_t)n * 5000 + i) * 79;
            if (t < 79) rem[t] |= row[t];
        }
        __syncthreads();
        if (stop) break;
    }
    __syncthreads();
    int na = st[0]; if (na > 100) na = 100;
    for (int r = t; r < 100; r += 128) {
        int p; float sc;
        if (r < na) { p = alive[r]; sc = S[p]; }
        else { p = dead[r - na]; sc = 0.f; }
        const float* bb = sBox + (((size_t)n * 5000) + p) * 4;
        out[(n * 100 + r) * 4 + 0] = bb[0];
        out[(n * 100 + r) * 4 + 1] = bb[1];
        out[(n * 100 + r) * 4 + 2] = bb[2];
        out[(n * 100 + r) * 4 + 3] = bb[3];
        out[800 + n * 100 + r] = sc;
        out[1000 + n * 100 + r] = sCls[(size_t)n * 5000 + p];
    }
}

// ----------------------------------------------------------------------------
extern "C" void kernel_launch(void* const* d_in, const int* in_sizes, int n_in,
                              void* d_out, int out_size, void* d_ws, size_t ws_size,
                              hipStream_t stream)
{
    const float* feat[5] = { (const float*)d_in[0], (const float*)d_in[1],
                             (const float*)d_in[2], (const float*)d_in[3],
                             (const float*)d_in[4] };
    const float* cls_w   = (const float*)d_in[5];
    const float* cls_b   = (const float*)d_in[6];
    const float* box_w   = (const float*)d_in[7];
    const float* box_b   = (const float*)d_in[8];
    const float* score_w = (const float*)d_in[9];
    const float* score_b = (const float*)d_in[10];
    const float* pred_w  = (const float*)d_in[11];
    const float* pred_b  = (const float*)d_in[12];
    const float* ctr_w   = (const float*)d_in[13];
    const float* ctr_b   = (const float*)d_in[14];

    char* ws = (char*)d_ws;
    size_t off = 0;
    auto alloc = [&](size_t nbytes) -> void* {
        void* p = ws + off;
        off += (nbytes + 255) & ~(size_t)255;
        return p;
    };
    const int   LH[5]  = { 128, 64, 32, 16, 8 };
    const int   LW[5]  = { 168, 84, 42, 21, 11 };
    const float LS[5]  = { 8.f, 16.f, 32.f, 64.f, 128.f };
    const int   LHW[5] = { 21504, 5376, 1344, 336, 88 };
    long off81[5], offD[5];
    { long a = 0, d = 0;
      for (int l = 0; l < 5; ++l) { off81[l] = a; offD[l] = d; a += 2L * 81 * LHW[l]; d += 2L * 4 * LHW[l]; } }
    long off256_14[4];
    { long a = 0; for (int l = 0; l < 4; ++l) { off256_14[l] = a; a += 2L * 256 * LHW[l + 1]; } }
    long offL[5];
    { long a = 0; for (int l = 0; l < 5; ++l) { offL[l] = a; a += 2L * 256 * LHW[l]; } }
    const size_t allE = (size_t)offL[4] + 2L * 256 * LHW[4];

    // common buffers
    float* lg81   = (float*)alloc(sizeof(float) * (off81[4] + 2L * 81 * LHW[4]));
    float* deltas = (float*)alloc(sizeof(float) * (offD[4] + 2L * 4 * LHW[4]));
    float* packw  = (float*)alloc(sizeof(float) * 81 * 2304);
    float* packb  = (float*)alloc(sizeof(float) * 128);
    unsigned* hist = (unsigned*)alloc(sizeof(unsigned) * 10 * 4096);
    int* sel       = (int*)alloc(sizeof(int) * 10 * 8);
    int* counters  = (int*)alloc(sizeof(int) * 10 * 2);
    unsigned* eqList = (unsigned*)alloc(sizeof(unsigned) * 10 * 4096);
    int* candIdx     = (int*)alloc(sizeof(int) * 2 * 5000);
    float* candScore = (float*)alloc(sizeof(float) * 2 * 5000);
    float* candZ     = (float*)alloc(sizeof(float) * 2 * 5000);
    float* candBox   = (float*)alloc(sizeof(float) * 2 * 5000 * 4);
    int* candCls     = (int*)alloc(sizeof(int) * 2 * 5000);
    float* sBox   = (float*)alloc(sizeof(float) * 2 * 5000 * 4);
    float* sScore = (float*)alloc(sizeof(float) * 2 * 5000);
    float* sCls   = (float*)alloc(sizeof(float) * 2 * 5000);
    float* sOffB  = (float*)alloc(sizeof(float) * 2 * 5000 * 4);
    float* sArea  = (float*)alloc(sizeof(float) * 2 * 5000);

    const size_t bigB0 = sizeof(float) * allE;                 // 58.67 MB (merged)
    const size_t bigB1 = sizeof(float) * 2L * 256 * LHW[0];    // 44.04 MB (lvl0 only)
    const size_t pad0 = (bigB0 + 255) & ~(size_t)255;
    const size_t pad1 = (bigB1 + 255) & ~(size_t)255;
    bool t0 = (ws_size >= off + 4 * pad0 + (1u << 20));
    bool t1 = !t0 && (ws_size >= off + 4 * pad1 + (1u << 20));

    float* clsP; float* clsQ; float* boxP; float* boxQ;
    if (t0) {
        clsP = (float*)alloc(bigB0); clsQ = (float*)alloc(bigB0);
        boxP = (float*)alloc(bigB0); boxQ = (float*)alloc(bigB0);
    } else if (t1) {
        clsP = (float*)alloc(bigB1); clsQ = (float*)alloc(bigB1);
        boxP = (float*)alloc(bigB1); boxQ = (float*)alloc(bigB1);
    } else {
        clsP = (float*)alloc(bigB1); clsQ = (float*)alloc(bigB1);
        boxP = clsP; boxQ = clsQ;
    }
    unsigned long long* masks = (unsigned long long*)clsP;  // reused post-conv

    pack_kernel<<<(81 * 2304 + 255) / 256, 256, 0, stream>>>(score_w, score_b, ctr_w, ctr_b, packw, packb);

    const size_t WS = 589824;  // 256*256*9

    // swizzled grid size: tile-groups per XCD, 8 XCDs, 2*NZ blocks per tile
    auto gsz = [](int nTiles, int NZ) { return ((nTiles + 7) / 8) * 8 * 2 * NZ; };

    if (t0) {
        // --- merged all-5-level cfgs ---
        MCfg cA{}, cAf{}, cAh{};
        for (int l = 0; l < 5; ++l) {
            cA.feat[l] = feat[l];
            cA.offIn[l] = offL[l];
            cA.offOutA[l] = offL[l];
            cA.offOutB[l] = offL[l];
            cA.tilesX[l] = (LW[l] + 15) / 16;
            cA.Hs[l] = LH[l]; cA.Ws[l] = LW[l];
        }
        cA.tileBase[0] = 0;   cA.tileBase[1] = 176; cA.tileBase[2] = 224;
        cA.tileBase[3] = 236; cA.tileBase[4] = 240; cA.tileBase[5] = 241;
        cA.nLvl = 5; cA.useFeats = 0;
        cAf = cA; cAf.useFeats = 1;
        cAh = cA;
        for (int l = 0; l < 5; ++l) { cAh.offOutA[l] = off81[l]; cAh.offOutB[l] = offD[l]; }

        int gT = gsz(241, 8), gH = gsz(241, 4);
        conv_g<1,4><<<gT, 256, 0, stream>>>(cAf, feat[0], feat[0], cls_w + 0 * WS, box_w + 0 * WS, cls_b + 0,   box_b + 0,   clsP, boxP, 256, 256, 4, 0, 241, 8);
        conv_g<1,4><<<gT, 256, 0, stream>>>(cA,  clsP,    boxP,    cls_w + 1 * WS, box_w + 1 * WS, cls_b + 256, box_b + 256, clsQ, boxQ, 256, 256, 4, 0, 241, 8);
        conv_g<1,4><<<gT, 256, 0, stream>>>(cA,  clsQ,    boxQ,    cls_w + 2 * WS, box_w + 2 * WS, cls_b + 512, box_b + 512, clsP, boxP, 256, 256, 4, 0, 241, 8);
        conv_g<1,4><<<gT, 256, 0, stream>>>(cA,  clsP,    boxP,    cls_w + 3 * WS, box_w + 3 * WS, cls_b + 768, box_b + 768, clsQ, boxQ, 256, 256, 4, 0, 241, 8);
        // head: CC=2, z = 3 cls/ctr chunks (32 couts each, 81 used) + 1 pred chunk
        conv_g<0,2><<<gH, 256, 0, stream>>>(cAh, clsQ,    boxQ,    packw,          pred_w,         packb,       pred_b,      lg81, deltas, 81, 4, 3, 0, 241, 4);
    } else {
        // --- lvl0 / lvl1-4 split cfgs ---
        MCfg c0{}, c0f{}, c0h{}, c14{}, c14f{}, c14h{};
        c0.feat[0] = feat[0];
        c0.tileBase[0] = 0; c0.tileBase[1] = 176;
        c0.tilesX[0] = 11; c0.Hs[0] = 128; c0.Ws[0] = 168;
        c0.nLvl = 1; c0.useFeats = 0;
        c0f = c0; c0f.useFeats = 1;
        c0h = c0;  // head offsets both 0 for lvl0
        for (int l = 0; l < 4; ++l) {
            c14.feat[l] = feat[l + 1];
            c14.offIn[l] = off256_14[l];
            c14.offOutA[l] = off256_14[l];
            c14.offOutB[l] = off256_14[l];
            c14.tilesX[l] = (LW[l + 1] + 15) / 16;
            c14.Hs[l] = LH[l + 1]; c14.Ws[l] = LW[l + 1];
        }
        c14.tileBase[0] = 0; c14.tileBase[1] = 48; c14.tileBase[2] = 60;
        c14.tileBase[3] = 64; c14.tileBase[4] = 65;
        c14.nLvl = 4; c14.useFeats = 0;
        c14f = c14; c14f.useFeats = 1;
        c14h = c14;
        for (int l = 0; l < 4; ++l) { c14h.offOutA[l] = off81[l + 1]; c14h.offOutB[l] = offD[l + 1]; }

        if (t1) {
            int gT0 = gsz(176, 8), gH0 = gsz(176, 4);
            conv_g<1,4><<<gT0, 256, 0, stream>>>(c0f, feat[0], feat[0], cls_w + 0 * WS, box_w + 0 * WS, cls_b + 0,   box_b + 0,   clsP, boxP, 256, 256, 4, 0, 176, 8);
            conv_g<1,4><<<gT0, 256, 0, stream>>>(c0,  clsP,    boxP,    cls_w + 1 * WS, box_w + 1 * WS, cls_b + 256, box_b + 256, clsQ, boxQ, 256, 256, 4, 0, 176, 8);
            conv_g<1,4><<<gT0, 256, 0, stream>>>(c0,  clsQ,    boxQ,    cls_w + 2 * WS, box_w + 2 * WS, cls_b + 512, box_b + 512, clsP, boxP, 256, 256, 4, 0, 176, 8);
            conv_g<1,4><<<gT0, 256, 0, stream>>>(c0,  clsP,    boxP,    cls_w + 3 * WS, box_w + 3 * WS, cls_b + 768, box_b + 768, clsQ, boxQ, 256, 256, 4, 0, 176, 8);
            conv_g<0,2><<<gH0, 256, 0, stream>>>(c0h, clsQ,    boxQ,    packw,          pred_w,         packb,       pred_b,      lg81, deltas, 81, 4, 3, 0, 176, 4);
            int gT1 = gsz(65, 8), gH1 = gsz(65, 4);
            conv_g<1,4><<<gT1, 256, 0, stream>>>(c14f, feat[1], feat[1], cls_w + 0 * WS, box_w + 0 * WS, cls_b + 0,   box_b + 0,   clsP, boxP, 256, 256, 4, 0, 65, 8);
            conv_g<1,4><<<gT1, 256, 0, stream>>>(c14,  clsP,    boxP,    cls_w + 1 * WS, box_w + 1 * WS, cls_b + 256, box_b + 256, clsQ, boxQ, 256, 256, 4, 0, 65, 8);
            conv_g<1,4><<<gT1, 256, 0, stream>>>(c14,  clsQ,    boxQ,    cls_w + 2 * WS, box_w + 2 * WS, cls_b + 512, box_b + 512, clsP, boxP, 256, 256, 4, 0, 65, 8);
            conv_g<1,4><<<gT1, 256, 0, stream>>>(c14,  clsP,    boxP,    cls_w + 3 * WS, box_w + 3 * WS, cls_b + 768, box_b + 768, clsQ, boxQ, 256, 256, 4, 0, 65, 8);
            conv_g<0,2><<<gH1, 256, 0, stream>>>(c14h, clsQ,    boxQ,    packw,          pred_w,         packb,       pred_b,      lg81, deltas, 81, 4, 3, 0, 65, 4);
        } else {
            // sequential towers sharing clsP/clsQ
            int gT0 = gsz(176, 4), gHL0 = gsz(176, 3), gHP0 = gsz(176, 1);
            conv_g<1,4><<<gT0, 256, 0, stream>>>(c0f, feat[0], feat[0], cls_w + 0 * WS, cls_w, cls_b + 0,   cls_b, clsP, clsP, 256, 256, 4, 0, 176, 4);
            conv_g<1,4><<<gT0, 256, 0, stream>>>(c0,  clsP,    clsP,    cls_w + 1 * WS, cls_w, cls_b + 256, cls_b, clsQ, clsQ, 256, 256, 4, 0, 176, 4);
            conv_g<1,4><<<gT0, 256, 0, stream>>>(c0,  clsQ,    clsQ,    cls_w + 2 * WS, cls_w, cls_b + 512, cls_b, clsP, clsP, 256, 256, 4, 0, 176, 4);
            conv_g<1,4><<<gT0, 256, 0, stream>>>(c0,  clsP,    clsP,    cls_w + 3 * WS, cls_w, cls_b + 768, cls_b, clsQ, clsQ, 256, 256, 4, 0, 176, 4);
            conv_g<0,2><<<gHL0, 256, 0, stream>>>(c0h, clsQ,   clsQ,    packw,          packw, packb,       packb, lg81, lg81, 81, 81, 3, 0, 176, 3);
            conv_g<1,4><<<gT0, 256, 0, stream>>>(c0f, feat[0], feat[0], box_w + 0 * WS, box_w, box_b + 0,   box_b, clsP, clsP, 256, 256, 4, 0, 176, 4);
            conv_g<1,4><<<gT0, 256, 0, stream>>>(c0,  clsP,    clsP,    box_w + 1 * WS, box_w, box_b + 256, box_b, clsQ, clsQ, 256, 256, 4, 0, 176, 4);
            conv_g<1,4><<<gT0, 256, 0, stream>>>(c0,  clsQ,    clsQ,    box_w + 2 * WS, box_w, box_b + 512, box_b, clsP, clsP, 256, 256, 4, 0, 176, 4);
            conv_g<1,4><<<gT0, 256, 0, stream>>>(c0,  clsP,    clsP,    box_w + 3 * WS, box_w, box_b + 768, box_b, clsQ, clsQ, 256, 256, 4, 0, 176, 4);
            conv_g<0,2><<<gHP0, 256, 0, stream>>>(c0h, clsQ,   clsQ,    pred_w,         pred_w, pred_b,    pred_b, deltas, deltas, 0, 4, 0, 0, 176, 1);
            int gT1 = gsz(65, 4), gHL1 = gsz(65, 3), gHP1 = gsz(65, 1);
            MCfg c14hP = c14h;
            conv_g<1,4><<<gT1, 256, 0, stream>>>(c14f, feat[1], feat[1], cls_w + 0 * WS, cls_w, cls_b + 0,   cls_b, clsP, clsP, 256, 256, 4, 0, 65, 4);
            conv_g<1,4><<<gT1, 256, 0, stream>>>(c14,  clsP,    clsP,    cls_w + 1 * WS, cls_w, cls_b + 256, cls_b, clsQ, clsQ, 256, 256, 4, 0, 65, 4);
            conv_g<1,4><<<gT1, 256, 0, stream>>>(c14,  clsQ,    clsQ,    cls_w + 2 * WS, cls_w, cls_b + 512, cls_b, clsP, clsP, 256, 256, 4, 0, 65, 4);
            conv_g<1,4><<<gT1, 256, 0, stream>>>(c14,  clsP,    clsP,    cls_w + 3 * WS, cls_w, cls_b + 768, cls_b, clsQ, clsQ, 256, 256, 4, 0, 65, 4);
            conv_g<0,2><<<gHL1, 256, 0, stream>>>(c14h, clsQ,  clsQ,    packw,          packw, packb,       packb, lg81, lg81, 81, 81, 3, 0, 65, 3);
            conv_g<1,4><<<gT1, 256, 0, stream>>>(c14f, feat[1], feat[1], box_w + 0 * WS, box_w, box_b + 0,   box_b, clsP, clsP, 256, 256, 4, 0, 65, 4);
            conv_g<1,4><<<gT1, 256, 0, stream>>>(c14,  clsP,    clsP,    box_w + 1 * WS, box_w, box_b + 256, box_b, clsQ, clsQ, 256, 256, 4, 0, 65, 4);
            conv_g<1,4><<<gT1, 256, 0, stream>>>(c14,  clsQ,    clsQ,    box_w + 2 * WS, box_w, box_b + 512, box_b, clsP, clsP, 256, 256, 4, 0, 65, 4);
            conv_g<1,4><<<gT1, 256, 0, stream>>>(c14,  clsP,    clsP,    box_w + 3 * WS, box_w, box_b + 768, box_b, clsQ, clsQ, 256, 256, 4, 0, 65, 4);
            conv_g<0,2><<<gHP1, 256, 0, stream>>>(c14hP, clsQ, clsQ,    pred_w,         pred_w, pred_b,    pred_b, deltas, deltas, 0, 4, 0, 0, 65, 1);
        }
    }

    // --- batched selection pipeline ---
    LvlT T{};
    for (int l = 0; l < 5; ++l) {
        T.HW[l] = LHW[l]; T.W[l] = LW[l]; T.stride[l] = LS[l];
        T.off81[l] = off81[l]; T.offD[l] = offD[l];
    }
    dim3 gHist(128, 2, 5);
    hipMemsetAsync(hist, 0, 10 * 4096 * sizeof(unsigned), stream);
    hist_b<<<gHist, 256, 0, stream>>>(T, lg81, hist, sel, 0);
    scan_b<<<10, 1024, 0, stream>>>(hist, sel, 0);
    hipMemsetAsync(hist, 0, 10 * 4096 * sizeof(unsigned), stream);
    hist_b<<<gHist, 256, 0, stream>>>(T, lg81, hist, sel, 1);
    scan_b<<<10, 1024, 0, stream>>>(hist, sel, 1);
    hipMemsetAsync(hist, 0, 10 * 4096 * sizeof(unsigned), stream);
    hist_b<<<gHist, 256, 0, stream>>>(T, lg81, hist, sel, 2);
    scan_b<<<10, 1024, 0, stream>>>(hist, sel, 2);
    hipMemsetAsync(counters, 0, 10 * 2 * sizeof(int), stream);
    compact_b<<<gHist, 256, 0, stream>>>(T, lg81, sel, candIdx, candScore, eqList, counters);
    eqfinish_b<<<10, 256, 0, stream>>>(eqList, sel, counters, candIdx, candScore);
    lvlsort_b<<<10, 256, 0, stream>>>(candIdx, candScore);
    decode_b<<<(2 * 5000 + 255) / 256, 256, 0, stream>>>(T, candIdx, candScore, deltas,
                                                         candBox, candZ, candCls);
    gsort_kernel<<<2, 1024, 0, stream>>>(candZ, candBox, candCls, sBox, sScore, sCls, sOffB, sArea);
    dim3 gM(79, 79, 2);
    nms_mask_kernel<<<gM, 64, 0, stream>>>(sOffB, sArea, masks);
    nms_scan_kernel<<<2, 128, 0, stream>>>(masks, sScore, sBox, sCls, (float*)d_out);
}

// Round 14
// 8764.085 us; speedup vs baseline: 1.0576x; 1.0576x over previous
//
#include <hip/hip_runtime.h>
#include <math.h>

#define NCLS 80
#define KTOP 1000
#define SCORE_T 0.05f
#define NMS_T 0.6f
#define SCALE_CLAMP 4.135166556742356f
#define IMGW 1344.0f
#define IMGH 1024.0f

// ----------------------------------------------------------------------------
// Multi-level 3x3 same-pad conv, Cin=256, dual-tower via z. 256 thr ->
// (16*CC) couts x (8x16) tile; thread: CC couts x (2x4) pos. ci-block 8
// (r12-proven: 12.8KB LDS, 32% occ; r13's ci=16 lost occupancy), LDS input
// double-buffer (1 barrier/rstep). Weights via running pointers (+72/rstep)
// and explicit component fmaf chain (r10-12 proven: 84 VGPR). 1-D grid with
// XCD-aware decode (r11-proven: FETCH -48%). r14: staging col = j*4+q
// (was q*5+j) -> 4 lanes/segment coalesced global reads + conflict-free LDS
// writes; same element set, bit-exact. FMA order per output: ci asc,
// (dy,dx) asc, fmaf — bit-identical to r4..r12.
// ----------------------------------------------------------------------------
struct MCfg {
    const float* feat[5];
    long offIn[5];
    long offOutA[5];
    long offOutB[5];
    int tileBase[6];
    int tilesX[5];
    int Hs[5];
    int Ws[5];
    int nLvl;
    int useFeats;
};

template<int RELU, int CC>
__global__ __launch_bounds__(256)
void conv_g(MCfg cfg,
            const float* __restrict__ inA, const float* __restrict__ inB,
            const float* __restrict__ wA, const float* __restrict__ wB,
            const float* __restrict__ bA, const float* __restrict__ bB,
            float* __restrict__ outA, float* __restrict__ outB,
            int CoutA, int CoutB, int zA, int zOff, int nTiles, int NZ)
{
    __shared__ float sIn[2][8][10][20];
    const int tid = threadIdx.x;

    // XCD-aware block decode: tile % 8 == blockIdx.x % 8 (same-XCD grouping)
    const int bx   = blockIdx.x;
    const int xcd  = bx & 7;
    const int rest = bx >> 3;
    const int perT = 2 * NZ;
    const int tgroup = rest / perT;
    const int k      = rest - tgroup * perT;
    const int tile   = tgroup * 8 + xcd;
    if (tile >= nTiles) return;
    const int n     = k / NZ;
    const int z_eff = (k - n * NZ) + zOff;

    const bool isA = (z_eff < zA);
    const float* wt   = isA ? wA : wB;
    const float* bias = isA ? bA : bB;
    const int Cout    = isA ? CoutA : CoutB;
    const int cbase   = (isA ? z_eff : z_eff - zA) * (16 * CC);

    int tl = tile;
    int lvl = 0;
    while (lvl + 1 < cfg.nLvl && tl >= cfg.tileBase[lvl + 1]) ++lvl;
    int t = tl - cfg.tileBase[lvl];
    const int tX = cfg.tilesX[lvl];
    int ty = 0;
    while (t >= tX) { t -= tX; ++ty; }
    const int tx = t;
    const int H = cfg.Hs[lvl], W = cfg.Ws[lvl], HW = H * W;
    const float* inbase = cfg.useFeats ? cfg.feat[lvl]
                                       : ((isA ? inA : inB) + cfg.offIn[lvl]);
    const float* inN = inbase + (size_t)n * 256 * HW;

    const int h0 = ty * 8, w0 = tx * 16;
    const int cell = tid & 15, cg = tid >> 4;
    const int pr = (cell >> 2) << 1;   // 0,2,4,6
    const int pc = (cell & 3) << 2;    // 0,4,8,12
    const int q = tid & 3, pp0 = tid >> 2;

    const int cout_my = cbase + cg * CC;
    // running weight pointers, bumped +72 floats per rstep
    const float* wptr[CC];
#pragma unroll
    for (int cc = 0; cc < CC; ++cc) {
        int gc = cout_my + cc;
        int gcw = (gc < Cout) ? gc : 0;
        wptr[cc] = wt + (size_t)gcw * 2304;
    }

    float acc[CC][8];
#pragma unroll
    for (int a = 0; a < CC; ++a)
#pragma unroll
        for (int b = 0; b < 8; ++b) acc[a][b] = 0.f;

    float rIn[10];

    auto issue = [&](int ci0) {
#pragma unroll
        for (int it = 0; it < 2; ++it) {
            int p = pp0 + it * 64;
            if (p < 80) {
                int ci = p / 10, row = p - ci * 10;
                int gh = h0 + row - 1;
                const float* src = inN + (size_t)(ci0 + ci) * HW;
#pragma unroll
                for (int j = 0; j < 5; ++j) {
                    int col = j * 4 + q, gw = w0 + col - 1;   // r14: lane-consecutive
                    float v = 0.f;
                    if (col < 18 && (unsigned)gh < (unsigned)H && (unsigned)gw < (unsigned)W)
                        v = src[(long)gh * W + gw];
                    rIn[it * 5 + j] = v;
                }
            }
        }
    };
    auto commit = [&](int buf) {
#pragma unroll
        for (int it = 0; it < 2; ++it) {
            int p = pp0 + it * 64;
            if (p < 80) {
                int ci = p / 10, row = p - ci * 10;
#pragma unroll
                for (int j = 0; j < 5; ++j) {
                    int col = j * 4 + q;
                    if (col < 18) sIn[buf][ci][row][col] = rIn[it * 5 + j];
                }
            }
        }
    };

    issue(0);
    commit(0);
    __syncthreads();

    for (int r = 0; r < 32; ++r) {
        if (r < 31) issue((r + 1) * 8);
        const int cur = r & 1;
#pragma unroll 2
        for (int ci = 0; ci < 8; ++ci) {
            float x[4][6];
#pragma unroll
            for (int rr = 0; rr < 4; ++rr)
#pragma unroll
                for (int c = 0; c < 6; ++c) x[rr][c] = sIn[cur][ci][pr + rr][pc + c];
#pragma unroll
            for (int cc = 0; cc < CC; ++cc) {
                const float* wp = wptr[cc] + ci * 9;   // ci*9 folds to imm offset
                float4 wa = *(const float4*)(wp);
                float4 wb = *(const float4*)(wp + 4);
                float w8 = wp[8];
#pragma unroll
                for (int py = 0; py < 2; ++py)
#pragma unroll
                    for (int px = 0; px < 4; ++px) {
                        float s = acc[cc][py * 4 + px];
                        // (dy,dx) ascending — identical order to wv[dy*3+dx]
                        s = fmaf(wa.x, x[py + 0][px + 0], s);
                        s = fmaf(wa.y, x[py + 0][px + 1], s);
                        s = fmaf(wa.z, x[py + 0][px + 2], s);
                        s = fmaf(wa.w, x[py + 1][px + 0], s);
                        s = fmaf(wb.x, x[py + 1][px + 1], s);
                        s = fmaf(wb.y, x[py + 1][px + 2], s);
                        s = fmaf(wb.z, x[py + 2][px + 0], s);
                        s = fmaf(wb.w, x[py + 2][px + 1], s);
                        s = fmaf(w8,   x[py + 2][px + 2], s);
                        acc[cc][py * 4 + px] = s;
                    }
            }
        }
#pragma unroll
        for (int cc = 0; cc < CC; ++cc) wptr[cc] += 72;
        if (r < 31) commit((r + 1) & 1);
        __syncthreads();
    }

    float* outbase = isA ? (outA + cfg.offOutA[lvl]) : (outB + cfg.offOutB[lvl]);
#pragma unroll
    for (int cc = 0; cc < CC; ++cc) {
        int gc = cout_my + cc;
        if (gc >= Cout) continue;
        float b = bias[gc];
        float* outc = outbase + ((size_t)n * Cout + gc) * HW;
#pragma unroll
        for (int py = 0; py < 2; ++py) {
            int gh = h0 + pr + py;
            if (gh >= H) continue;
#pragma unroll
            for (int px = 0; px < 4; ++px) {
                int gw = w0 + pc + px;
                if (gw >= W) continue;
                float v = acc[cc][py * 4 + px] + b;
                if (RELU) v = fmaxf(v, 0.f);
                outc[(long)gh * W + gw] = v;
            }
        }
    }
}

// ----------------------------------------------------------------------------
__global__ void pack_kernel(const float* __restrict__ sw, const float* __restrict__ sb,
                            const float* __restrict__ cw, const float* __restrict__ cb,
                            float* __restrict__ pw, float* __restrict__ pb)
{
    int i = blockIdx.x * 256 + threadIdx.x;
    const int tot = 81 * 2304;
    if (i < tot) pw[i] = (i < 80 * 2304) ? sw[i] : cw[i - 80 * 2304];
    if (i < 81)  pb[i] = (i < 80) ? sb[i] : cb[i - 80];
}

// ----------------------------------------------------------------------------
// batched selection pipeline (unchanged, proven absmax 0.0)
// ----------------------------------------------------------------------------
struct LvlT {
    int HW[5]; int W[5]; float stride[5];
    long off81[5]; long offD[5];
};

__device__ inline float score_at(const float* __restrict__ L, int HW, int c, int pos)
{
    float l = L[(size_t)c * HW + pos];
    float ct = L[(size_t)80 * HW + pos];
    float sl = 1.f / (1.f + expf(-l));
    float sc = 1.f / (1.f + expf(-ct));
    return sqrtf(sl * sc);
}

__global__ __launch_bounds__(256)
void hist_b(LvlT T, const float* __restrict__ lg, unsigned* __restrict__ hist,
            const int* __restrict__ sel, int pass)
{
    __shared__ unsigned h[4096];
    int n = blockIdx.y, lvl = blockIdx.z, g = lvl * 2 + n;
    int HW = T.HW[lvl];
    int nel = HW * 80;
    const float* L = lg + T.off81[lvl] + (size_t)n * 81 * HW;
    unsigned* Hh = hist + g * 4096;
    const int* SL = sel + g * 8;
    for (int i = threadIdx.x; i < 4096; i += 256) h[i] = 0;
    __syncthreads();
    unsigned b1 = 0, b2 = 0;
    if (pass >= 1) b1 = (unsigned)SL[0];
    if (pass == 2) b2 = (unsigned)SL[2];
    int stride = gridDim.x * 256;
    for (int i = blockIdx.x * 256 + threadIdx.x; i < nel; i += stride) {
        int c = i / HW, pos = i - c * HW;
        unsigned bits = __float_as_uint(score_at(L, HW, c, pos));
        if (pass == 0) atomicAdd(&h[bits >> 24], 1u);
        else if (pass == 1) { if ((bits >> 24) == b1) atomicAdd(&h[(bits >> 12) & 0xFFFu], 1u); }
        else { if ((bits >> 12) == ((b1 << 12) | b2)) atomicAdd(&h[bits & 0xFFFu], 1u); }
    }
    __syncthreads();
    for (int i = threadIdx.x; i < 4096; i += 256)
        if (h[i]) atomicAdd(&Hh[i], h[i]);
}

__global__ __launch_bounds__(1024)
void scan_b(const unsigned* __restrict__ hist, int* __restrict__ sel, int pass)
{
    __shared__ unsigned ps[1024];
    int g = blockIdx.x;
    const unsigned* H = hist + g * 4096;
    int* SL = sel + g * 8;
    int tid = threadIdx.x;
    unsigned s = 0;
    if (pass == 0) s = (tid < 256) ? H[tid] : 0u;
    else { for (int b = 0; b < 4; ++b) s += H[tid * 4 + b]; }
    ps[tid] = s;
    __syncthreads();
    if (tid == 0) {
        unsigned base = 0;
        if (pass == 1) base = (unsigned)SL[1];
        else if (pass == 2) base = (unsigned)SL[3];
        unsigned cum = base, prev = 0;
        int fb = -1;
        for (int t = 1023; t >= 0; --t) {
            if (cum + ps[t] >= (unsigned)KTOP) {
                if (pass == 0) { fb = t; prev = cum; }
                else {
                    for (int b = t * 4 + 3; b >= t * 4; --b) {
                        unsigned c = H[b];
                        if (cum + c >= (unsigned)KTOP) { fb = b; prev = cum; break; }
                        cum += c;
                    }
                }
                break;
            }
            cum += ps[t];
        }
        if (pass == 0) { SL[0] = fb; SL[1] = (int)prev; }
        else if (pass == 1) { SL[2] = fb; SL[3] = (int)prev; }
        else {
            unsigned T = (((unsigned)SL[0]) << 24) | (((unsigned)SL[2]) << 12) | (unsigned)fb;
            SL[4] = (int)T; SL[5] = KTOP - (int)prev; SL[6] = (int)prev;
        }
    }
}

__global__ __launch_bounds__(256)
void compact_b(LvlT T, const float* __restrict__ lg, const int* __restrict__ sel,
               int* __restrict__ candIdx, float* __restrict__ candScore,
               unsigned* __restrict__ eqList, int* __restrict__ counters)
{
    int n = blockIdx.y, lvl = blockIdx.z, g = lvl * 2 + n;
    int HW = T.HW[lvl];
    int nel = HW * 80;
    const float* L = lg + T.off81[lvl] + (size_t)n * 81 * HW;
    unsigned Tt = (unsigned)sel[g * 8 + 4];
    int* cnt = counters + g * 2;
    int stride = gridDim.x * 256;
    for (int i = blockIdx.x * 256 + threadIdx.x; i < nel; i += stride) {
        int c = i / HW, pos = i - c * HW;
        float v = score_at(L, HW, c, pos);
        unsigned bits = __float_as_uint(v);
        int flat = pos * 80 + c;
        if (bits > Tt) {
            int s = atomicAdd(&cnt[0], 1);
            if (s < KTOP) {
                candIdx[n * 5000 + lvl * 1000 + s] = flat;
                candScore[n * 5000 + lvl * 1000 + s] = v;
            }
        } else if (bits == Tt) {
            int e = atomicAdd(&cnt[1], 1);
            if (e < 4096) eqList[g * 4096 + e] = (unsigned)flat;
        }
    }
}

template<typename T>
__device__ inline void bitonicSort(T* a, int N, bool desc)
{
    for (int k = 2; k <= N; k <<= 1)
        for (int j = k >> 1; j >= 1; j >>= 1) {
            for (int i = threadIdx.x; i < N; i += blockDim.x) {
                int l = i ^ j;
                if (l > i) {
                    T x = a[i], y = a[l];
                    bool up = ((i & k) == 0);
                    bool sw = desc ? (up ? (x < y) : (x > y)) : (up ? (x > y) : (x < y));
                    if (sw) { a[i] = y; a[l] = x; }
                }
            }
            __syncthreads();
        }
}

__global__ __launch_bounds__(256)
void eqfinish_b(const unsigned* __restrict__ eqList, const int* __restrict__ sel,
                const int* __restrict__ counters, int* __restrict__ candIdx,
                float* __restrict__ candScore)
{
    __shared__ unsigned L[4096];
    int g = blockIdx.x;
    int lvl = g >> 1, n = g & 1;
    int e = counters[g * 2 + 1]; if (e > 4096) e = 4096;
    int needEq = sel[g * 8 + 5];
    int base = sel[g * 8 + 6];
    unsigned T = (unsigned)sel[g * 8 + 4];
    for (int i = threadIdx.x; i < 4096; i += 256) L[i] = (i < e) ? eqList[g * 4096 + i] : 0xFFFFFFFFu;
    __syncthreads();
    bitonicSort(L, 4096, false);
    for (int t = threadIdx.x; t < needEq; t += 256) {
        int s = base + t;
        if (s < KTOP) {
            candIdx[n * 5000 + lvl * 1000 + s] = (int)L[t];
            candScore[n * 5000 + lvl * 1000 + s] = __uint_as_float(T);
        }
    }
}

__global__ __launch_bounds__(256)
void lvlsort_b(int* __restrict__ candIdx, float* __restrict__ candScore)
{
    __shared__ unsigned long long K[1024];
    int g = blockIdx.x;
    int lvl = g >> 1, n = g & 1;
    int* CI = candIdx + n * 5000 + lvl * 1000;
    float* CS = candScore + n * 5000 + lvl * 1000;
    for (int i = threadIdx.x; i < 1024; i += blockDim.x)
        K[i] = (i < KTOP)
             ? ((((unsigned long long)(unsigned)CI[i]) << 32) | __float_as_uint(CS[i]))
             : 0xFFFFFFFFFFFFFFFFULL;
    __syncthreads();
    bitonicSort(K, 1024, false);
    for (int i = threadIdx.x; i < KTOP; i += blockDim.x) {
        CI[i] = (int)(K[i] >> 32);
        CS[i] = __uint_as_float((unsigned)(K[i] & 0xFFFFFFFFu));
    }
}

__global__ __launch_bounds__(256)
void decode_b(LvlT T, const int* __restrict__ candIdx, const float* __restrict__ candScore,
              const float* __restrict__ deltas, float* __restrict__ candBox,
              float* __restrict__ candZ, int* __restrict__ candCls)
{
    int t = blockIdx.x * 256 + threadIdx.x;
    if (t >= 2 * 5000) return;
    int n = t / 5000, r = t % 5000;
    int lvl = r / 1000;
    int HW = T.HW[lvl], W = T.W[lvl];
    float stride = T.stride[lvl];
    int g = n * 5000 + r;
    int idx = candIdx[g];
    float raw = candScore[g];
    int pos = idx / NCLS, cls = idx % NCLS;
    int hh = pos / W, ww = pos % W;
    float cxa0 = ((float)ww + 0.5f) * stride;
    float cya0 = ((float)hh + 0.5f) * stride;
    float half = 2.f * stride;
    float a0 = cxa0 - half, a1 = cya0 - half, a2 = cxa0 + half, a3 = cya0 + half;
    float wa = a2 - a0, ha = a3 - a1;
    float cxa = a0 + 0.5f * wa, cya = a1 + 0.5f * ha;
    const float* D = deltas + T.offD[lvl] + (size_t)n * 4 * HW;
    float dx = D[pos], dy = D[HW + pos], dw = D[2 * HW + pos], dh = D[3 * HW + pos];
    dw = fminf(dw, SCALE_CLAMP); dh = fminf(dh, SCALE_CLAMP);
    float cx = dx * wa + cxa, cy = dy * ha + cya;
    float w2 = expf(dw) * wa, h2 = expf(dh) * ha;
    float x1 = fminf(fmaxf(cx - 0.5f * w2, 0.f), IMGW);
    float y1 = fminf(fmaxf(cy - 0.5f * h2, 0.f), IMGH);
    float x2 = fminf(fmaxf(cx + 0.5f * w2, 0.f), IMGW);
    float y2 = fminf(fmaxf(cy + 0.5f * h2, 0.f), IMGH);
    candBox[g * 4 + 0] = x1; candBox[g * 4 + 1] = y1;
    candBox[g * 4 + 2] = x2; candBox[g * 4 + 3] = y2;
    candZ[g] = (raw > SCORE_T) ? raw : 0.f;
    candCls[g] = cls;
}

__global__ __launch_bounds__(1024)
void gsort_kernel(const float* __restrict__ candZ, const float* __restrict__ candBox,
                  const int* __restrict__ candCls, float* __restrict__ sBox,
                  float* __restrict__ sScore, float* __restrict__ sCls,
                  float* __restrict__ sOffB, float* __restrict__ sArea)
{
    __shared__ unsigned long long K[8192];
    int n = blockIdx.x;
    for (int i = threadIdx.x; i < 8192; i += 1024)
        K[i] = (i < 5000)
             ? ((((unsigned long long)__float_as_uint(candZ[n * 5000 + i])) << 16)
                | (unsigned long long)(65535 - i))
             : 0ULL;
    __syncthreads();
    bitonicSort(K, 8192, true);
    for (int r = threadIdx.x; r < 5000; r += 1024) {
        unsigned long long k = K[r];
        int g = 65535 - (int)(k & 0xFFFFULL);
        float s = __uint_as_float((unsigned)((k >> 16) & 0xFFFFFFFFULL));
        int cls = candCls[n * 5000 + g];
        float b0 = candBox[(n * 5000 + g) * 4 + 0];
        float b1 = candBox[(n * 5000 + g) * 4 + 1];
        float b2 = candBox[(n * 5000 + g) * 4 + 2];
        float b3 = candBox[(n * 5000 + g) * 4 + 3];
        size_t o = (size_t)n * 5000 + r;
        sBox[o * 4 + 0] = b0; sBox[o * 4 + 1] = b1; sBox[o * 4 + 2] = b2; sBox[o * 4 + 3] = b3;
        sScore[o] = s;
        sCls[o] = (float)cls;
        float off = (float)cls * 2000.0f;
        float o0 = b0 + off, o1 = b1 + off, o2 = b2 + off, o3 = b3 + off;
        sOffB[o * 4 + 0] = o0; sOffB[o * 4 + 1] = o1; sOffB[o * 4 + 2] = o2; sOffB[o * 4 + 3] = o3;
        sArea[o] = (o2 - o0) * (o3 - o1);
    }
}

__global__ __launch_bounds__(64)
void nms_mask_kernel(const float* __restrict__ sOffB, const float* __restrict__ sArea,
                     unsigned long long* __restrict__ masks)
{
    __shared__ float jb0[64], jb1[64], jb2[64], jb3[64], ja[64];
    int jw = blockIdx.x;
    int it = blockIdx.y;
    int n  = blockIdx.z;
    int t = threadIdx.x;
    int jj = jw * 64 + t;
    const float* B = sOffB + (size_t)n * 5000 * 4;
    const float* A = sArea + (size_t)n * 5000;
    if (jj < 5000) {
        jb0[t] = B[jj * 4]; jb1[t] = B[jj * 4 + 1];
        jb2[t] = B[jj * 4 + 2]; jb3[t] = B[jj * 4 + 3];
        ja[t] = A[jj];
    } else {
        jb0[t] = -3e8f; jb1[t] = -3e8f; jb2[t] = -3e8f; jb3[t] = -3e8f; ja[t] = 0.f;
    }
    __syncthreads();
    int i = it * 64 + t;
    if (i >= 5000) return;
    float b0 = B[i * 4], b1 = B[i * 4 + 1], b2 = B[i * 4 + 2], b3 = B[i * 4 + 3];
    float ai = A[i];
    unsigned long long m = 0;
    for (int u = 0; u < 64; ++u) {
        float xx1 = fmaxf(b0, jb0[u]);
        float yy1 = fmaxf(b1, jb1[u]);
        float xx2 = fminf(b2, jb2[u]);
        float yy2 = fminf(b3, jb3[u]);
        float iw = fmaxf(xx2 - xx1, 0.f), ih = fmaxf(yy2 - yy1, 0.f);
        float inter = iw * ih;
        float iou = inter / (ai + ja[u] - inter + 1e-9f);
        if (iou > NMS_T) m |= (1ull << u);
    }
    masks[((size_t)n * 5000 + i) * 79 + jw] = m;
}

__global__ __launch_bounds__(128)
void nms_scan_kernel(const unsigned long long* __restrict__ masks,
                     const float* __restrict__ sScore, const float* __restrict__ sBox,
                     const float* __restrict__ sCls, float* __restrict__ out)
{
    __shared__ unsigned long long rem[80];
    __shared__ int alive[100], dead[100];
    __shared__ int st[3];
    int n = blockIdx.x, t = threadIdx.x;
    const float* S = sScore + (size_t)n * 5000;
    for (int i = t; i < 80; i += 128) rem[i] = 0ull;
    if (t == 0) { st[0] = 0; st[1] = 0; }
    __syncthreads();
    for (int i = 0; i < 5000; ++i) {
        if (t == 0) {
            bool sup = (rem[i >> 6] >> (i & 63)) & 1ull;
            float s = S[i];
            bool al = (!sup) && (s > 0.f);
            st[2] = al ? 1 : 0;
            if (al) { if (st[0] < 100) alive[st[0]] = i; st[0]++; }
            else    { if (st[1] < 100) dead[st[1]] = i;  st[1]++; }
        }
        __syncthreads();
        bool stop = (st[0] >= 100);
        if (st[2] && !stop) {
            const unsigned long long* row = masks + ((size_t)n * 5000 + i) * 79;
            if (t < 79) rem[t] |= row[t];
        }
        __syncthreads();
        if (stop) break;
    }
    __syncthreads();
    int na = st[0]; if (na > 100) na = 100;
    for (int r = t; r < 100; r += 128) {
        int p; float sc;
        if (r < na) { p = alive[r]; sc = S[p]; }
        else { p = dead[r - na]; sc = 0.f; }
        const float* bb = sBox + (((size_t)n * 5000) + p) * 4;
        out[(n * 100 + r) * 4 + 0] = bb[0];
        out[(n * 100 + r) * 4 + 1] = bb[1];
        out[(n * 100 + r) * 4 + 2] = bb[2];
        out[(n * 100 + r) * 4 + 3] = bb[3];
        out[800 + n * 100 + r] = sc;
        out[1000 + n * 100 + r] = sCls[(size_t)n * 5000 + p];
    }
}

// ----------------------------------------------------------------------------
extern "C" void kernel_launch(void* const* d_in, const int* in_sizes, int n_in,
                              void* d_out, int out_size, void* d_ws, size_t ws_size,
                              hipStream_t stream)
{
    const float* feat[5] = { (const float*)d_in[0], (const float*)d_in[1],
                             (const float*)d_in[2], (const float*)d_in[3],
                             (const float*)d_in[4] };
    const float* cls_w   = (const float*)d_in[5];
    const float* cls_b   = (const float*)d_in[6];
    const float* box_w   = (const float*)d_in[7];
    const float* box_b   = (const float*)d_in[8];
    const float* score_w = (const float*)d_in[9];
    const float* score_b = (const float*)d_in[10];
    const float* pred_w  = (const float*)d_in[11];
    const float* pred_b  = (const float*)d_in[12];
    const float* ctr_w   = (const float*)d_in[13];
    const float* ctr_b   = (const float*)d_in[14];

    char* ws = (char*)d_ws;
    size_t off = 0;
    auto alloc = [&](size_t nbytes) -> void* {
        void* p = ws + off;
        off += (nbytes + 255) & ~(size_t)255;
        return p;
    };
    const int   LH[5]  = { 128, 64, 32, 16, 8 };
    const int   LW[5]  = { 168, 84, 42, 21, 11 };
    const float LS[5]  = { 8.f, 16.f, 32.f, 64.f, 128.f };
    const int   LHW[5] = { 21504, 5376, 1344, 336, 88 };
    long off81[5], offD[5];
    { long a = 0, d = 0;
      for (int l = 0; l < 5; ++l) { off81[l] = a; offD[l] = d; a += 2L * 81 * LHW[l]; d += 2L * 4 * LHW[l]; } }
    long off256_14[4];
    { long a = 0; for (int l = 0; l < 4; ++l) { off256_14[l] = a; a += 2L * 256 * LHW[l + 1]; } }
    long offL[5];
    { long a = 0; for (int l = 0; l < 5; ++l) { offL[l] = a; a += 2L * 256 * LHW[l]; } }
    const size_t allE = (size_t)offL[4] + 2L * 256 * LHW[4];

    // common buffers
    float* lg81   = (float*)alloc(sizeof(float) * (off81[4] + 2L * 81 * LHW[4]));
    float* deltas = (float*)alloc(sizeof(float) * (offD[4] + 2L * 4 * LHW[4]));
    float* packw  = (float*)alloc(sizeof(float) * 81 * 2304);
    float* packb  = (float*)alloc(sizeof(float) * 128);
    unsigned* hist = (unsigned*)alloc(sizeof(unsigned) * 10 * 4096);
    int* sel       = (int*)alloc(sizeof(int) * 10 * 8);
    int* counters  = (int*)alloc(sizeof(int) * 10 * 2);
    unsigned* eqList = (unsigned*)alloc(sizeof(unsigned) * 10 * 4096);
    int* candIdx     = (int*)alloc(sizeof(int) * 2 * 5000);
    float* candScore = (float*)alloc(sizeof(float) * 2 * 5000);
    float* candZ     = (float*)alloc(sizeof(float) * 2 * 5000);
    float* candBox   = (float*)alloc(sizeof(float) * 2 * 5000 * 4);
    int* candCls     = (int*)alloc(sizeof(int) * 2 * 5000);
    float* sBox   = (float*)alloc(sizeof(float) * 2 * 5000 * 4);
    float* sScore = (float*)alloc(sizeof(float) * 2 * 5000);
    float* sCls   = (float*)alloc(sizeof(float) * 2 * 5000);
    float* sOffB  = (float*)alloc(sizeof(float) * 2 * 5000 * 4);
    float* sArea  = (float*)alloc(sizeof(float) * 2 * 5000);

    const size_t bigB0 = sizeof(float) * allE;                 // 58.67 MB (merged)
    const size_t bigB1 = sizeof(float) * 2L * 256 * LHW[0];    // 44.04 MB (lvl0 only)
    const size_t pad0 = (bigB0 + 255) & ~(size_t)255;
    const size_t pad1 = (bigB1 + 255) & ~(size_t)255;
    bool t0 = (ws_size >= off + 4 * pad0 + (1u << 20));
    bool t1 = !t0 && (ws_size >= off + 4 * pad1 + (1u << 20));

    float* clsP; float* clsQ; float* boxP; float* boxQ;
    if (t0) {
        clsP = (float*)alloc(bigB0); clsQ = (float*)alloc(bigB0);
        boxP = (float*)alloc(bigB0); boxQ = (float*)alloc(bigB0);
    } else if (t1) {
        clsP = (float*)alloc(bigB1); clsQ = (float*)alloc(bigB1);
        boxP = (float*)alloc(bigB1); boxQ = (float*)alloc(bigB1);
    } else {
        clsP = (float*)alloc(bigB1); clsQ = (float*)alloc(bigB1);
        boxP = clsP; boxQ = clsQ;
    }
    unsigned long long* masks = (unsigned long long*)clsP;  // reused post-conv

    pack_kernel<<<(81 * 2304 + 255) / 256, 256, 0, stream>>>(score_w, score_b, ctr_w, ctr_b, packw, packb);

    const size_t WS = 589824;  // 256*256*9

    // swizzled grid size: tile-groups per XCD, 8 XCDs, 2*NZ blocks per tile
    auto gsz = [](int nTiles, int NZ) { return ((nTiles + 7) / 8) * 8 * 2 * NZ; };

    if (t0) {
        // --- merged all-5-level cfgs ---
        MCfg cA{}, cAf{}, cAh{};
        for (int l = 0; l < 5; ++l) {
            cA.feat[l] = feat[l];
            cA.offIn[l] = offL[l];
            cA.offOutA[l] = offL[l];
            cA.offOutB[l] = offL[l];
            cA.tilesX[l] = (LW[l] + 15) / 16;
            cA.Hs[l] = LH[l]; cA.Ws[l] = LW[l];
        }
        cA.tileBase[0] = 0;   cA.tileBase[1] = 176; cA.tileBase[2] = 224;
        cA.tileBase[3] = 236; cA.tileBase[4] = 240; cA.tileBase[5] = 241;
        cA.nLvl = 5; cA.useFeats = 0;
        cAf = cA; cAf.useFeats = 1;
        cAh = cA;
        for (int l = 0; l < 5; ++l) { cAh.offOutA[l] = off81[l]; cAh.offOutB[l] = offD[l]; }

        int gT = gsz(241, 8), gH = gsz(241, 4);
        conv_g<1,4><<<gT, 256, 0, stream>>>(cAf, feat[0], feat[0], cls_w + 0 * WS, box_w + 0 * WS, cls_b + 0,   box_b + 0,   clsP, boxP, 256, 256, 4, 0, 241, 8);
        conv_g<1,4><<<gT, 256, 0, stream>>>(cA,  clsP,    boxP,    cls_w + 1 * WS, box_w + 1 * WS, cls_b + 256, box_b + 256, clsQ, boxQ, 256, 256, 4, 0, 241, 8);
        conv_g<1,4><<<gT, 256, 0, stream>>>(cA,  clsQ,    boxQ,    cls_w + 2 * WS, box_w + 2 * WS, cls_b + 512, box_b + 512, clsP, boxP, 256, 256, 4, 0, 241, 8);
        conv_g<1,4><<<gT, 256, 0, stream>>>(cA,  clsP,    boxP,    cls_w + 3 * WS, box_w + 3 * WS, cls_b + 768, box_b + 768, clsQ, boxQ, 256, 256, 4, 0, 241, 8);
        // head: CC=2, z = 3 cls/ctr chunks (32 couts each, 81 used) + 1 pred chunk
        conv_g<0,2><<<gH, 256, 0, stream>>>(cAh, clsQ,    boxQ,    packw,          pred_w,         packb,       pred_b,      lg81, deltas, 81, 4, 3, 0, 241, 4);
    } else {
        // --- lvl0 / lvl1-4 split cfgs ---
        MCfg c0{}, c0f{}, c0h{}, c14{}, c14f{}, c14h{};
        c0.feat[0] = feat[0];
        c0.tileBase[0] = 0; c0.tileBase[1] = 176;
        c0.tilesX[0] = 11; c0.Hs[0] = 128; c0.Ws[0] = 168;
        c0.nLvl = 1; c0.useFeats = 0;
        c0f = c0; c0f.useFeats = 1;
        c0h = c0;  // head offsets both 0 for lvl0
        for (int l = 0; l < 4; ++l) {
            c14.feat[l] = feat[l + 1];
            c14.offIn[l] = off256_14[l];
            c14.offOutA[l] = off256_14[l];
            c14.offOutB[l] = off256_14[l];
            c14.tilesX[l] = (LW[l + 1] + 15) / 16;
            c14.Hs[l] = LH[l + 1]; c14.Ws[l] = LW[l + 1];
        }
        c14.tileBase[0] = 0; c14.tileBase[1] = 48; c14.tileBase[2] = 60;
        c14.tileBase[3] = 64; c14.tileBase[4] = 65;
        c14.nLvl = 4; c14.useFeats = 0;
        c14f = c14; c14f.useFeats = 1;
        c14h = c14;
        for (int l = 0; l < 4; ++l) { c14h.offOutA[l] = off81[l + 1]; c14h.offOutB[l] = offD[l + 1]; }

        if (t1) {
            int gT0 = gsz(176, 8), gH0 = gsz(176, 4);
            conv_g<1,4><<<gT0, 256, 0, stream>>>(c0f, feat[0], feat[0], cls_w + 0 * WS, box_w + 0 * WS, cls_b + 0,   box_b + 0,   clsP, boxP, 256, 256, 4, 0, 176, 8);
            conv_g<1,4><<<gT0, 256, 0, stream>>>(c0,  clsP,    boxP,    cls_w + 1 * WS, box_w + 1 * WS, cls_b + 256, box_b + 256, clsQ, boxQ, 256, 256, 4, 0, 176, 8);
            conv_g<1,4><<<gT0, 256, 0, stream>>>(c0,  clsQ,    boxQ,    cls_w + 2 * WS, box_w + 2 * WS, cls_b + 512, box_b + 512, clsP, boxP, 256, 256, 4, 0, 176, 8);
            conv_g<1,4><<<gT0, 256, 0, stream>>>(c0,  clsP,    boxP,    cls_w + 3 * WS, box_w + 3 * WS, cls_b + 768, box_b + 768, clsQ, boxQ, 256, 256, 4, 0, 176, 8);
            conv_g<0,2><<<gH0, 256, 0, stream>>>(c0h, clsQ,    boxQ,    packw,          pred_w,         packb,       pred_b,      lg81, deltas, 81, 4, 3, 0, 176, 4);
            int gT1 = gsz(65, 8), gH1 = gsz(65, 4);
            conv_g<1,4><<<gT1, 256, 0, stream>>>(c14f, feat[1], feat[1], cls_w + 0 * WS, box_w + 0 * WS, cls_b + 0,   box_b + 0,   clsP, boxP, 256, 256, 4, 0, 65, 8);
            conv_g<1,4><<<gT1, 256, 0, stream>>>(c14,  clsP,    boxP,    cls_w + 1 * WS, box_w + 1 * WS, cls_b + 256, box_b + 256, clsQ, boxQ, 256, 256, 4, 0, 65, 8);
            conv_g<1,4><<<gT1, 256, 0, stream>>>(c14,  clsQ,    boxQ,    cls_w + 2 * WS, box_w + 2 * WS, cls_b + 512, box_b + 512, clsP, boxP, 256, 256, 4, 0, 65, 8);
            conv_g<1,4><<<gT1, 256, 0, stream>>>(c14,  clsP,    boxP,    cls_w + 3 * WS, box_w + 3 * WS, cls_b + 768, box_b + 768, clsQ, boxQ, 256, 256, 4, 0, 65, 8);
            conv_g<0,2><<<gH1, 256, 0, stream>>>(c14h, clsQ,    boxQ,    packw,          pred_w,         packb,       pred_b,      lg81, deltas, 81, 4, 3, 0, 65, 4);
        } else {
            // sequential towers sharing clsP/clsQ
            int gT0 = gsz(176, 4), gHL0 = gsz(176, 3), gHP0 = gsz(176, 1);
            conv_g<1,4><<<gT0, 256, 0, stream>>>(c0f, feat[0], feat[0], cls_w + 0 * WS, cls_w, cls_b + 0,   cls_b, clsP, clsP, 256, 256, 4, 0, 176, 4);
            conv_g<1,4><<<gT0, 256, 0, stream>>>(c0,  clsP,    clsP,    cls_w + 1 * WS, cls_w, cls_b + 256, cls_b, clsQ, clsQ, 256, 256, 4, 0, 176, 4);
            conv_g<1,4><<<gT0, 256, 0, stream>>>(c0,  clsQ,    clsQ,    cls_w + 2 * WS, cls_w, cls_b + 512, cls_b, clsP, clsP, 256, 256, 4, 0, 176, 4);
            conv_g<1,4><<<gT0, 256, 0, stream>>>(c0,  clsP,    clsP,    cls_w + 3 * WS, cls_w, cls_b + 768, cls_b, clsQ, clsQ, 256, 256, 4, 0, 176, 4);
            conv_g<0,2><<<gHL0, 256, 0, stream>>>(c0h, clsQ,   clsQ,    packw,          packw, packb,       packb, lg81, lg81, 81, 81, 3, 0, 176, 3);
            conv_g<1,4><<<gT0, 256, 0, stream>>>(c0f, feat[0], feat[0], box_w + 0 * WS, box_w, box_b + 0,   box_b, clsP, clsP, 256, 256, 4, 0, 176, 4);
            conv_g<1,4><<<gT0, 256, 0, stream>>>(c0,  clsP,    clsP,    box_w + 1 * WS, box_w, box_b + 256, box_b, clsQ, clsQ, 256, 256, 4, 0, 176, 4);
            conv_g<1,4><<<gT0, 256, 0, stream>>>(c0,  clsQ,    clsQ,    box_w + 2 * WS, box_w, box_b + 512, box_b, clsP, clsP, 256, 256, 4, 0, 176, 4);
            conv_g<1,4><<<gT0, 256, 0, stream>>>(c0,  clsP,    clsP,    box_w + 3 * WS, box_w, box_b + 768, box_b, clsQ, clsQ, 256, 256, 4, 0, 176, 4);
            conv_g<0,2><<<gHP0, 256, 0, stream>>>(c0h, clsQ,   clsQ,    pred_w,         pred_w, pred_b,    pred_b, deltas, deltas, 0, 4, 0, 0, 176, 1);
            int gT1 = gsz(65, 4), gHL1 = gsz(65, 3), gHP1 = gsz(65, 1);
            MCfg c14hP = c14h;
            conv_g<1,4><<<gT1, 256, 0, stream>>>(c14f, feat[1], feat[1], cls_w + 0 * WS, cls_w, cls_b + 0,   cls_b, clsP, clsP, 256, 256, 4, 0, 65, 4);
            conv_g<1,4><<<gT1, 256, 0, stream>>>(c14,  clsP,    clsP,    cls_w + 1 * WS, cls_w, cls_b + 256, cls_b, clsQ, clsQ, 256, 256, 4, 0, 65, 4);
            conv_g<1,4><<<gT1, 256, 0, stream>>>(c14,  clsQ,    clsQ,    cls_w + 2 * WS, cls_w, cls_b + 512, cls_b, clsP, clsP, 256, 256, 4, 0, 65, 4);
            conv_g<1,4><<<gT1, 256, 0, stream>>>(c14,  clsP,    clsP,    cls_w + 3 * WS, cls_w, cls_b + 768, cls_b, clsQ, clsQ, 256, 256, 4, 0, 65, 4);
            conv_g<0,2><<<gHL1, 256, 0, stream>>>(c14h, clsQ,  clsQ,    packw,          packw, packb,       packb, lg81, lg81, 81, 81, 3, 0, 65, 3);
            conv_g<1,4><<<gT1, 256, 0, stream>>>(c14f, feat[1], feat[1], box_w + 0 * WS, box_w, box_b + 0,   box_b, clsP, clsP, 256, 256, 4, 0, 65, 4);
            conv_g<1,4><<<gT1, 256, 0, stream>>>(c14,  clsP,    clsP,    box_w + 1 * WS, box_w, box_b + 256, box_b, clsQ, clsQ, 256, 256, 4, 0, 65, 4);
            conv_g<1,4><<<gT1, 256, 0, stream>>>(c14,  clsQ,    clsQ,    box_w + 2 * WS, box_w, box_b + 512, box_b, clsP, clsP, 256, 256, 4, 0, 65, 4);
            conv_g<1,4><<<gT1, 256, 0, stream>>>(c14,  clsP,    clsP,    box_w + 3 * WS, box_w, box_b + 768, box_b, clsQ, clsQ, 256, 256, 4, 0, 65, 4);
            conv_g<0,2><<<gHP1, 256, 0, stream>>>(c14hP, clsQ, clsQ,    pred_w,         pred_w, pred_b,    pred_b, deltas, deltas, 0, 4, 0, 0, 65, 1);
        }
    }

    // --- batched selection pipeline ---
    LvlT T{};
    for (int l = 0; l < 5; ++l) {
        T.HW[l] = LHW[l]; T.W[l] = LW[l]; T.stride[l] = LS[l];
        T.off81[l] = off81[l]; T.offD[l] = offD[l];
    }
    dim3 gHist(128, 2, 5);
    hipMemsetAsync(hist, 0, 10 * 4096 * sizeof(unsigned), stream);
    hist_b<<<gHist, 256, 0, stream>>>(T, lg81, hist, sel, 0);
    scan_b<<<10, 1024, 0, stream>>>(hist, sel, 0);
    hipMemsetAsync(hist, 0, 10 * 4096 * sizeof(unsigned), stream);
    hist_b<<<gHist, 256, 0, stream>>>(T, lg81, hist, sel, 1);
    scan_b<<<10, 1024, 0, stream>>>(hist, sel, 1);
    hipMemsetAsync(hist, 0, 10 * 4096 * sizeof(unsigned), stream);
    hist_b<<<gHist, 256, 0, stream>>>(T, lg81, hist, sel, 2);
    scan_b<<<10, 1024, 0, stream>>>(hist, sel, 2);
    hipMemsetAsync(counters, 0, 10 * 2 * sizeof(int), stream);
    compact_b<<<gHist, 256, 0, stream>>>(T, lg81, sel, candIdx, candScore, eqList, counters);
    eqfinish_b<<<10, 256, 0, stream>>>(eqList, sel, counters, candIdx, candScore);
    lvlsort_b<<<10, 256, 0, stream>>>(candIdx, candScore);
    decode_b<<<(2 * 5000 + 255) / 256, 256, 0, stream>>>(T, candIdx, candScore, deltas,
                                                         candBox, candZ, candCls);
    gsort_kernel<<<2, 1024, 0, stream>>>(candZ, candBox, candCls, sBox, sScore, sCls, sOffB, sArea);
    dim3 gM(79, 79, 2);
    nms_mask_kernel<<<gM, 64, 0, stream>>>(sOffB, sArea, masks);
    nms_scan_kernel<<<2, 128, 0, stream>>>(masks, sScore, sBox, sCls, (float*)d_out);
}